// Round 4
// baseline (187.770 us; speedup 1.0000x reference)
//
#include <hip/hip_runtime.h>

#define LL 32
#define LDP 33
#define TT 1024

// ws layout (floats)
#define MS_OFF 0                        // 1024 * 1024 floats (Ms, compact [t][i][j])
#define P0_OFF (MS_OFF + TT * 1024)     // 128 leaf-product matrices
#define P1_OFF (P0_OFF + 128 * 1024)    // 8 matrices

// ---- lse-semiring matmul step: A row in this thread's 32-lane group (reg a),
// ---- B column j in LDS (stride LDP). Register-lean t[16] max tree.
__device__ __forceinline__ float lse_mul_step(float a, const float* Bcol) {
  float s[LL];
  #pragma unroll
  for (int k = 0; k < LL; k++) s[k] = __shfl(a, k, 32) + Bcol[k * LDP];
  float t[16];
  #pragma unroll
  for (int k = 0; k < 16; k++) t[k] = fmaxf(s[k], s[k + 16]);
  #pragma unroll
  for (int st = 8; st >= 1; st >>= 1) {
    #pragma unroll
    for (int k = 0; k < st; k++) t[k] = fmaxf(t[k], t[k + st]);
  }
  const float mx = t[0];
  float a0 = 0.f, a1 = 0.f, a2 = 0.f, a3 = 0.f;
  #pragma unroll
  for (int k = 0; k < LL; k += 4) {
    a0 += __expf(s[k]     - mx);
    a1 += __expf(s[k + 1] - mx);
    a2 += __expf(s[k + 2] - mx);
    a3 += __expf(s[k + 3] - mx);
  }
  return mx + __logf((a0 + a1) + (a2 + a3));
}

// ---- ordered product of R staged matrices via binary tree (depth log2 R).
// ---- id0: replace slot 0 by the exact lse-identity (diag 0, else -1e30).
template <int R>
__device__ __forceinline__ float lse_tree(float (*S)[LL][LDP], int i, int j, bool id0) {
  float c[R / 2];
  #pragma unroll
  for (int p = 0; p < R / 2; p++) {
    float a = (p == 0 && id0) ? ((i == j) ? 0.f : -1e30f) : S[2 * p][i][j];
    c[p] = lse_mul_step(a, &S[2 * p + 1][0][j]);
    __builtin_amdgcn_sched_barrier(0);   // bound register pressure
  }
  #pragma unroll
  for (int n = R / 2; n > 1; n >>= 1) {
    __syncthreads();                     // all reads of S slots done
    #pragma unroll
    for (int q = 0; q < n / 2; q++) S[2 * q + 1][i][j] = c[2 * q + 1];
    __syncthreads();
    #pragma unroll
    for (int q = 0; q < n / 2; q++) {
      c[q] = lse_mul_step(c[2 * q], &S[2 * q + 1][0][j]);
      __builtin_amdgcn_sched_barrier(0);
    }
  }
  return c[0];
}

// ---- K1: pure streaming GEMV. Ms[cell] = dot(X[cell, 0:128], w).
// ---- 2048 blocks x 256 threads; block covers 512 contiguous cells (256 KiB read).
__global__ __launch_bounds__(256) void crf_gemv(
    const float4* __restrict__ X4, const float* __restrict__ w,
    float* __restrict__ ms) {
  __shared__ float sm[512];
  const int tid = threadIdx.x, l5 = tid & 31, g = tid >> 5;  // 8 groups/block
  const float4 w4 = reinterpret_cast<const float4*>(w)[l5];
  const size_t cbase = (size_t)blockIdx.x * 512;
  const float4* xp = X4 + cbase * 32;
  #pragma unroll 8
  for (int it = 0; it < 64; it++) {
    const int cell = it * 8 + g;
    const float4 xv = xp[cell * 32 + l5];
    float v = fmaf(xv.x, w4.x, fmaf(xv.y, w4.y, fmaf(xv.z, w4.z, xv.w * w4.w)));
    v += __shfl_xor(v, 16, 32);
    v += __shfl_xor(v,  8, 32);
    v += __shfl_xor(v,  4, 32);
    v += __shfl_xor(v,  2, 32);
    v += __shfl_xor(v,  1, 32);
    if (l5 == 0) sm[cell] = v;
  }
  __syncthreads();
  if (tid < 128)
    reinterpret_cast<float4*>(ms + cbase)[tid] = reinterpret_cast<const float4*>(sm)[tid];
}

// ---- K2: leaf products, radix 8. Block b -> product of Ms[8b .. 8b+7].
// ---- Block 0 excludes Ms[0] (it feeds alpha0) via identity.
__global__ __launch_bounds__(1024, 1) void crf_leaf8(
    const float* __restrict__ ms, float* __restrict__ p0) {
  __shared__ float S[8][LL][LDP];
  const int blk = blockIdx.x, tid = threadIdx.x;
  const int i = tid >> 5, j = tid & 31;
  #pragma unroll
  for (int m = 0; m < 8; m++) S[m][i][j] = ms[((size_t)blk * 8 + m) * 1024 + tid];
  __syncthreads();
  const float r = lse_tree<8>(S, i, j, blk == 0);
  p0[(size_t)blk * 1024 + tid] = r;
}

// ---- K3: combine radix 16. Block b -> product of P0[16b .. 16b+15].
__global__ __launch_bounds__(1024, 1) void crf_comb16(
    const float* __restrict__ src, float* __restrict__ dst) {
  __shared__ float S[16][LL][LDP];
  const int blk = blockIdx.x, tid = threadIdx.x;
  const int i = tid >> 5, j = tid & 31;
  #pragma unroll
  for (int m = 0; m < 16; m++) S[m][i][j] = src[((size_t)blk * 16 + m) * 1024 + tid];
  __syncthreads();
  const float r = lse_tree<16>(S, i, j, false);
  dst[(size_t)blk * 1024 + tid] = r;
}

// ---- K4: product of the 8 P1 mats, then logZ + parallel path gather.
__global__ __launch_bounds__(1024, 1) void crf_final(
    const float* __restrict__ ws, const int* __restrict__ label,
    float* __restrict__ out) {
  __shared__ float S[8][LL][LDP];
  __shared__ float redm[16], reds[16], redp[16];
  const int tid = threadIdx.x, i = tid >> 5, j = tid & 31;
  #pragma unroll
  for (int m = 0; m < 8; m++) S[m][i][j] = ws[P1_OFF + m * 1024 + tid];
  __syncthreads();
  const float a = lse_tree<8>(S, i, j, false);
  // v(i,j) = alpha0[i] + P[i][j];  logZ = lse over all (i,j)
  const float v = ws[MS_OFF + i] + a;          // alpha0[i] = Ms[0][0][i]
  // path gather: t = tid, fully parallel
  const int lab = label[tid];
  const int pv = (tid == 0) ? 0 : label[tid - 1];     // BEG = 0
  const float pval = ws[MS_OFF + (size_t)tid * 1024 + pv * 32 + lab];
  float mx = v;
  #pragma unroll
  for (int o = 32; o >= 1; o >>= 1) mx = fmaxf(mx, __shfl_xor(mx, o));
  const int wid = tid >> 6, lane = tid & 63;
  if (lane == 0) redm[wid] = mx;
  __syncthreads();
  float mb = redm[0];
  #pragma unroll
  for (int q = 1; q < 16; q++) mb = fmaxf(mb, redm[q]);
  float e = __expf(v - mb);
  float p = pval;
  #pragma unroll
  for (int o = 32; o >= 1; o >>= 1) {
    e += __shfl_xor(e, o);
    p += __shfl_xor(p, o);
  }
  if (lane == 0) { reds[wid] = e; redp[wid] = p; }
  __syncthreads();
  if (tid == 0) {
    float s = 0.f, ps = 0.f;
    for (int q = 0; q < 16; q++) { s += reds[q]; ps += redp[q]; }
    out[0] = -ps + (mb + __logf(s));
  }
}

extern "C" void kernel_launch(void* const* d_in, const int* in_sizes, int n_in,
                              void* d_out, int out_size, void* d_ws, size_t ws_size,
                              hipStream_t stream) {
  const float4* X4 = (const float4*)d_in[0];
  const float* w = (const float*)d_in[1];
  const int* label = (const int*)d_in[2];
  float* out = (float*)d_out;
  float* ws = (float*)d_ws;

  crf_gemv<<<2048, 256, 0, stream>>>(X4, w, ws + MS_OFF);
  crf_leaf8<<<128, 1024, 0, stream>>>(ws + MS_OFF, ws + P0_OFF);
  crf_comb16<<<8, 1024, 0, stream>>>(ws + P0_OFF, ws + P1_OFF);
  crf_final<<<1, 1024, 0, stream>>>(ws, label, out);
}

// Round 5
// 162.834 us; speedup vs baseline: 1.1531x; 1.1531x over previous
//
#include <hip/hip_runtime.h>

#define LL 32
#define LDP 33
#define TT 1024

// ws layout (floats)
#define MS_OFF 0                        // 1024*1024 floats: Ms[t][i][j]
#define P0_OFF (MS_OFF + TT * 1024)     // 128 leaf products
#define P1_OFF (P0_OFF + 128 * 1024)    // 8 products

// lse-semiring matmul step: A row lives in this thread's 32-lane group (reg a),
// B column j in LDS (stride LDP). Register-lean: s[32]+t[16] ~ 56 live regs.
__device__ __forceinline__ float lse_mul_step(float a, const float* Bcol) {
  float s[LL];
  #pragma unroll
  for (int k = 0; k < LL; k++) s[k] = __shfl(a, k, 32) + Bcol[k * LDP];
  float t[16];
  #pragma unroll
  for (int k = 0; k < 16; k++) t[k] = fmaxf(s[k], s[k + 16]);
  #pragma unroll
  for (int st = 8; st >= 1; st >>= 1) {
    #pragma unroll
    for (int k = 0; k < st; k++) t[k] = fmaxf(t[k], t[k + st]);
  }
  const float mx = t[0];
  float a0 = 0.f, a1 = 0.f, a2 = 0.f, a3 = 0.f;
  #pragma unroll
  for (int k = 0; k < LL; k += 4) {
    a0 += __expf(s[k]     - mx);
    a1 += __expf(s[k + 1] - mx);
    a2 += __expf(s[k + 2] - mx);
    a3 += __expf(s[k + 3] - mx);
  }
  return mx + __logf((a0 + a1) + (a2 + a3));
}

// ---- K1: streaming GEMV, 8 lanes per row. Lane (r8,l8) accumulates a
// ---- private partial over 16 k's of its row; only 3 shfl_xor per row.
__global__ __launch_bounds__(256, 4) void crf_gemv(
    const float4* __restrict__ X4, const float* __restrict__ w,
    float* __restrict__ ms) {
  __shared__ float sm[512];
  const int tid = threadIdx.x;
  const int wv = tid >> 6;        // wave 0..3
  const int l  = tid & 63;
  const int r8 = l >> 3;          // row-within-8
  const int l8 = l & 7;           // float4-column offset
  float4 wq[4];
  #pragma unroll
  for (int i = 0; i < 4; i++)
    wq[i] = reinterpret_cast<const float4*>(w)[i * 8 + l8];
  const size_t rowbase = (size_t)blockIdx.x * 512;
  const float4* xp = X4 + rowbase * 32;

  #pragma unroll 2
  for (int it = 0; it < 16; it++) {         // 32 rows per iteration
    const int row = it * 32 + wv * 8 + r8;
    const float4* rp = xp + (size_t)row * 32;
    float acc = 0.f;
    #pragma unroll
    for (int i = 0; i < 4; i++) {
      const float4 xv = rp[i * 8 + l8];     // 8 dense 128B segments per wave-load
      acc = fmaf(xv.x, wq[i].x, acc);
      acc = fmaf(xv.y, wq[i].y, acc);
      acc = fmaf(xv.z, wq[i].z, acc);
      acc = fmaf(xv.w, wq[i].w, acc);
    }
    acc += __shfl_xor(acc, 1);
    acc += __shfl_xor(acc, 2);
    acc += __shfl_xor(acc, 4);
    if (l8 == 0) sm[row] = acc;
  }
  __syncthreads();
  if (tid < 128)
    reinterpret_cast<float4*>(ms + rowbase)[tid] =
        reinterpret_cast<const float4*>(sm)[tid];
}

// ---- K2: leaf products radix 8, sequential chain (register-lean).
// ---- Block 0 replaces Ms[0] (alpha0's source) by the exact lse-identity.
__global__ __launch_bounds__(1024, 1) void crf_leaf8(
    const float* __restrict__ ms, float* __restrict__ p0) {
  __shared__ float S[8][LL][LDP];
  const int blk = blockIdx.x, tid = threadIdx.x;
  const int i = tid >> 5, j = tid & 31;
  #pragma unroll
  for (int m = 0; m < 8; m++) S[m][i][j] = ms[((size_t)blk * 8 + m) * 1024 + tid];
  __syncthreads();
  float a = (blk == 0) ? ((i == j) ? 0.f : -1e30f) : S[0][i][j];
  #pragma unroll
  for (int m = 1; m < 8; m++) a = lse_mul_step(a, &S[m][0][j]);
  p0[(size_t)blk * 1024 + tid] = a;
}

// ---- K3: combine radix 16, sequential chain.
__global__ __launch_bounds__(1024, 1) void crf_comb16(
    const float* __restrict__ src, float* __restrict__ dst) {
  __shared__ float S[16][LL][LDP];
  const int blk = blockIdx.x, tid = threadIdx.x;
  const int i = tid >> 5, j = tid & 31;
  #pragma unroll
  for (int m = 0; m < 16; m++)
    S[m][i][j] = src[((size_t)blk * 16 + m) * 1024 + tid];
  __syncthreads();
  float a = S[0][i][j];
  #pragma unroll
  for (int m = 1; m < 16; m++) a = lse_mul_step(a, &S[m][0][j]);
  dst[(size_t)blk * 1024 + tid] = a;
}

// ---- K4: product of 8 P1 mats, logZ, parallel path gather, output.
__global__ __launch_bounds__(1024, 1) void crf_final(
    const float* __restrict__ ws, const int* __restrict__ label,
    float* __restrict__ out) {
  __shared__ float S[8][LL][LDP];
  __shared__ float redm[16], reds[16], redp[16];
  const int tid = threadIdx.x, i = tid >> 5, j = tid & 31;
  #pragma unroll
  for (int m = 0; m < 8; m++) S[m][i][j] = ws[P1_OFF + m * 1024 + tid];
  __syncthreads();
  float a = S[0][i][j];
  #pragma unroll
  for (int m = 1; m < 8; m++) a = lse_mul_step(a, &S[m][0][j]);
  // logZ = lse over (i,j) of alpha0[i] + P[i][j];  alpha0[i] = Ms[0][0][i]
  const float v = ws[MS_OFF + i] + a;
  const int lab = label[tid];
  const int pv = (tid == 0) ? 0 : label[tid - 1];     // BEG = 0
  const float pval = ws[MS_OFF + (size_t)tid * 1024 + pv * 32 + lab];
  float mx = v;
  #pragma unroll
  for (int o = 32; o >= 1; o >>= 1) mx = fmaxf(mx, __shfl_xor(mx, o));
  const int wid = tid >> 6, lane = tid & 63;
  if (lane == 0) redm[wid] = mx;
  __syncthreads();
  float mb = redm[0];
  #pragma unroll
  for (int q = 1; q < 16; q++) mb = fmaxf(mb, redm[q]);
  float e = __expf(v - mb);
  float p = pval;
  #pragma unroll
  for (int o = 32; o >= 1; o >>= 1) {
    e += __shfl_xor(e, o);
    p += __shfl_xor(p, o);
  }
  if (lane == 0) { reds[wid] = e; redp[wid] = p; }
  __syncthreads();
  if (tid == 0) {
    float s = 0.f, ps = 0.f;
    for (int q = 0; q < 16; q++) { s += reds[q]; ps += redp[q]; }
    out[0] = -ps + (mb + __logf(s));
  }
}

extern "C" void kernel_launch(void* const* d_in, const int* in_sizes, int n_in,
                              void* d_out, int out_size, void* d_ws, size_t ws_size,
                              hipStream_t stream) {
  const float4* X4 = (const float4*)d_in[0];
  const float* w = (const float*)d_in[1];
  const int* label = (const int*)d_in[2];
  float* out = (float*)d_out;
  float* ws = (float*)d_ws;

  crf_gemv<<<2048, 256, 0, stream>>>(X4, w, ws + MS_OFF);
  crf_leaf8<<<128, 1024, 0, stream>>>(ws + MS_OFF, ws + P0_OFF);
  crf_comb16<<<8, 1024, 0, stream>>>(ws + P0_OFF, ws + P1_OFF);
  crf_final<<<1, 1024, 0, stream>>>(ws, label, out);
}

// Round 6
// 156.363 us; speedup vs baseline: 1.2009x; 1.0414x over previous
//
#include <hip/hip_runtime.h>

#define TT 1024
#define LL 32
#define CHUNK 4
#define NBLK (TT / CHUNK)   // 256 blocks

// ws float offsets
#define ALPHA0_OFF 0                       // 32: alpha0 = Ms[0][BEG][:]
#define PATH_OFF   32                      // 256 path partials
#define P0_OFF     288                     // 256 chunk-product mats (1024 ea)
#define Q1_OFF     (P0_OFF + 256 * 1024)   // 32 mats
#define Q2_OFF     (Q1_OFF + 32 * 1024)    // 4 mats

// All-LDS lse-semiring cell (R1-proven register footprint, exact max-tree).
__device__ __forceinline__ float lse_cell(const float A[LL][LL + 1],
                                          const float B[LL][LL + 1],
                                          int i, int j) {
  float s[LL];
  #pragma unroll
  for (int k = 0; k < LL; k++) s[k] = A[i][k] + B[k][j];
  float t[16];
  #pragma unroll
  for (int k = 0; k < 16; k++) t[k] = fmaxf(s[k], s[k + 16]);
  #pragma unroll
  for (int st = 8; st >= 1; st >>= 1) {
    #pragma unroll
    for (int k = 0; k < st; k++) t[k] = fmaxf(t[k], t[k + st]);
  }
  const float mx = t[0];
  float a0 = 0.f, a1 = 0.f, a2 = 0.f, a3 = 0.f;
  #pragma unroll
  for (int k = 0; k < LL; k += 4) {
    a0 += __expf(s[k]     - mx);
    a1 += __expf(s[k + 1] - mx);
    a2 += __expf(s[k + 2] - mx);
    a3 += __expf(s[k + 3] - mx);
  }
  return mx + __logf((a0 + a1) + (a2 + a3));
}

// Stage A: R1-verbatim structure (1 KiB contiguous per wave-load), unroll 8.
__global__ __launch_bounds__(1024, 1) void crf_stageA(
    const float4* __restrict__ X4, const float* __restrict__ w,
    const int* __restrict__ label, float* __restrict__ ws) {
  __shared__ float Ms[CHUNK][LL][LL + 1];
  __shared__ float Pb[2][LL][LL + 1];
  const int blk = blockIdx.x, tid = threadIdx.x;
  const int l5 = tid & 31;
  const int half = (tid >> 5) & 1;
  const int wid = tid >> 6;
  const int cellbase = wid * 2 + half;   // 0..31
  const float4 w4 = reinterpret_cast<const float4*>(w)[l5];
  const int t0 = blk * CHUNK;

  #pragma unroll
  for (int m = 0; m < CHUNK; m++) {
    #pragma unroll 8
    for (int it = 0; it < LL; it++) {
      const int cell = it * LL + cellbase;
      float4 xv = X4[(size_t)(t0 + m) * 1024u * 32u + (size_t)cell * 32u + l5];
      float v = fmaf(xv.x, w4.x, fmaf(xv.y, w4.y, fmaf(xv.z, w4.z, xv.w * w4.w)));
      v += __shfl_xor(v, 16, 32);
      v += __shfl_xor(v,  8, 32);
      v += __shfl_xor(v,  4, 32);
      v += __shfl_xor(v,  2, 32);
      v += __shfl_xor(v,  1, 32);
      if (l5 == 0) Ms[m][it][cellbase] = v;
    }
  }
  __syncthreads();

  if (tid == 0) {
    float ps = 0.f;
    for (int m = 0; m < CHUNK; m++) {
      const int t = t0 + m;
      const int lab = label[t];
      const int pv = (t == 0) ? 0 : label[t - 1];   // BEG = 0
      ps += Ms[m][pv][lab];
    }
    ws[PATH_OFF + blk] = ps;
  }
  if (blk == 0 && tid < LL) ws[ALPHA0_OFF + tid] = Ms[0][0][tid];

  // in-block chunk product (R1 verbatim)
  const int i = tid >> 5, j = tid & 31;
  const int first = (blk == 0) ? 1 : 0;   // Ms[0] feeds alpha0, not the product
  Pb[0][i][j] = lse_cell(Ms[first], Ms[first + 1], i, j);
  int cur = 0;
  for (int m = first + 2; m < CHUNK; m++) {
    __syncthreads();
    float r = lse_cell(Pb[cur], Ms[m], i, j);
    Pb[cur ^ 1][i][j] = r;
    cur ^= 1;
  }
  ws[P0_OFF + blk * 1024 + tid] = Pb[cur][i][j];
}

// comb8: block b -> ordered product of src[8b..8b+7] via binary tree (3 rounds).
__global__ __launch_bounds__(1024, 1) void crf_comb8(
    const float* __restrict__ src, float* __restrict__ dst) {
  __shared__ float S[8][LL][LL + 1];
  __shared__ float PQ[4][LL][LL + 1];
  const int blk = blockIdx.x, tid = threadIdx.x;
  const int i = tid >> 5, j = tid & 31;
  #pragma unroll
  for (int m = 0; m < 8; m++)
    S[m][i][j] = src[((size_t)blk * 8 + m) * 1024 + tid];
  __syncthreads();
  #pragma unroll
  for (int q = 0; q < 4; q++)
    PQ[q][i][j] = lse_cell(S[2 * q], S[2 * q + 1], i, j);  // round 1 (4 parallel)
  __syncthreads();
  S[0][i][j] = lse_cell(PQ[0], PQ[1], i, j);               // round 2 (2 parallel)
  S[1][i][j] = lse_cell(PQ[2], PQ[3], i, j);
  __syncthreads();
  dst[(size_t)blk * 1024 + tid] = lse_cell(S[0], S[1], i, j);  // round 3
}

// final4: product of 4 mats (depth 2) + logZ + path sum + output.
__global__ __launch_bounds__(1024, 1) void crf_final4(
    const float* __restrict__ ws, float* __restrict__ out) {
  __shared__ float S[4][LL][LL + 1];
  __shared__ float PQ[2][LL][LL + 1];
  __shared__ float redm[16], reds[16], redp[16];
  const int tid = threadIdx.x, i = tid >> 5, j = tid & 31;
  #pragma unroll
  for (int m = 0; m < 4; m++) S[m][i][j] = ws[Q2_OFF + m * 1024 + tid];
  __syncthreads();
  PQ[0][i][j] = lse_cell(S[0], S[1], i, j);
  PQ[1][i][j] = lse_cell(S[2], S[3], i, j);
  __syncthreads();
  const float a = lse_cell(PQ[0], PQ[1], i, j);
  const float v = ws[ALPHA0_OFF + i] + a;

  float mx = v;
  #pragma unroll
  for (int o = 32; o >= 1; o >>= 1) mx = fmaxf(mx, __shfl_xor(mx, o));
  const int wv = tid >> 6, lane = tid & 63;
  if (lane == 0) redm[wv] = mx;
  __syncthreads();
  float mb = redm[0];
  #pragma unroll
  for (int q = 1; q < 16; q++) mb = fmaxf(mb, redm[q]);
  float e = __expf(v - mb);
  float p = (tid < 256) ? ws[PATH_OFF + tid] : 0.f;
  #pragma unroll
  for (int o = 32; o >= 1; o >>= 1) {
    e += __shfl_xor(e, o);
    p += __shfl_xor(p, o);
  }
  if (lane == 0) { reds[wv] = e; redp[wv] = p; }
  __syncthreads();
  if (tid == 0) {
    float s = 0.f, ps = 0.f;
    for (int q = 0; q < 16; q++) { s += reds[q]; ps += redp[q]; }
    out[0] = -ps + (mb + __logf(s));
  }
}

extern "C" void kernel_launch(void* const* d_in, const int* in_sizes, int n_in,
                              void* d_out, int out_size, void* d_ws, size_t ws_size,
                              hipStream_t stream) {
  const float4* X4 = (const float4*)d_in[0];
  const float* w = (const float*)d_in[1];
  const int* label = (const int*)d_in[2];
  float* out = (float*)d_out;
  float* ws = (float*)d_ws;

  crf_stageA<<<NBLK, 1024, 0, stream>>>(X4, w, label, ws);
  crf_comb8<<<32, 1024, 0, stream>>>(ws + P0_OFF, ws + Q1_OFF);   // 256 -> 32
  crf_comb8<<<4, 1024, 0, stream>>>(ws + Q1_OFF, ws + Q2_OFF);    //  32 -> 4
  crf_final4<<<1, 1024, 0, stream>>>(ws, out);
}